// Round 9
// baseline (190.502 us; speedup 1.0000x reference)
//
#include <hip/hip_runtime.h>

typedef __attribute__((ext_vector_type(8))) short short8;
typedef __attribute__((ext_vector_type(4))) float f32x4;
typedef unsigned long long u64;

#define N_NODES 100000
#define N_EDGES 1600000
#define IN_F 128
#define OUT_ALL 64   // HEADS*OUT_F
#define HEADS 4
#define OUT_F 16
#define NTILES (N_NODES / 16)         // 6250 exactly
#define SC_BLOCKS 1024                // scatter role: blocks 0..1023
#define PROJ_BLOCKS 1536
#define TOTAL_BLOCKS (SC_BLOCKS + PROJ_BLOCKS)

static __device__ __forceinline__ ushort f2bf(float f) {
    unsigned u = __float_as_uint(f);
    return (ushort)((u + 0x7FFF + ((u >> 16) & 1)) >> 16);   // RN, no NaN inputs
}
static __device__ __forceinline__ float bf2f(ushort b) {
    return __uint_as_float(((unsigned)b) << 16);
}
static __device__ __forceinline__ short8 pack_bf16x8(float4 f0, float4 f1) {
    union { unsigned u[4]; short8 s; } r;
    asm("v_cvt_pk_bf16_f32 %0, %1, %2" : "=v"(r.u[0]) : "v"(f0.x), "v"(f0.y));
    asm("v_cvt_pk_bf16_f32 %0, %1, %2" : "=v"(r.u[1]) : "v"(f0.z), "v"(f0.w));
    asm("v_cvt_pk_bf16_f32 %0, %1, %2" : "=v"(r.u[2]) : "v"(f1.x), "v"(f1.y));
    asm("v_cvt_pk_bf16_f32 %0, %1, %2" : "=v"(r.u[3]) : "v"(f1.z), "v"(f1.w));
    return r.s;
}

// ---- Kernel 1: fused MFMA projection + linked-list scatter ---------------
// Scatter (blocks 0..1023): old = atomicExch(&head[dst], e);
//   link[e] = (old<<32)|src  -- dense coalesced 8B stores, no RFO, no cap,
//   single pass over ei (no slice re-scan). 1 atomic/edge = the R7-measured
//   irreducible coherence tax; everything else is now well-formed traffic.
// Proj (blocks 1024..2559): 4 waves = 4 heads, W-frags in regs, MFMA
//   16x16x32 bf16, grid-stride over 16-node M-tiles (unchanged from R6).
__global__ __launch_bounds__(256) void proj_scatter_kernel(
    const float* __restrict__ x, const float* __restrict__ W,
    const float* __restrict__ att_i, const float* __restrict__ att_j,
    const int* __restrict__ ei,
    ushort* __restrict__ hb, float* __restrict__ ai, float* __restrict__ aj,
    int* __restrict__ head, u64* __restrict__ link)
{
    if (blockIdx.x < SC_BLOCKS) {
        const int4* __restrict__ srcp = (const int4*)ei;
        const int4* __restrict__ dstp = (const int4*)(ei + N_EDGES);
        for (int e4 = blockIdx.x * 256 + threadIdx.x; e4 < N_EDGES / 4;
             e4 += SC_BLOCKS * 256) {
            int4 s = srcp[e4];
            int4 d = dstp[e4];
            int e = e4 * 4;
            int o0 = atomicExch(&head[d.x], e + 0);
            int o1 = atomicExch(&head[d.y], e + 1);
            int o2 = atomicExch(&head[d.z], e + 2);
            int o3 = atomicExch(&head[d.w], e + 3);
            link[e + 0] = ((u64)(unsigned)o0 << 32) | (unsigned)s.x;
            link[e + 1] = ((u64)(unsigned)o1 << 32) | (unsigned)s.y;
            link[e + 2] = ((u64)(unsigned)o2 << 32) | (unsigned)s.z;
            link[e + 3] = ((u64)(unsigned)o3 << 32) | (unsigned)s.w;
        }
        return;
    }
    int bproj = blockIdx.x - SC_BLOCKS;        // 0..1535
    const int nproj = PROJ_BLOCKS;

    int w   = threadIdx.x >> 6;    // wave id == head == 16-col n-tile
    int l   = threadIdx.x & 63;
    int col = l & 15;
    int kg  = l >> 4;              // k-group 0..3 (8 k each)

    // B-frags: rows of W (f32 -> bf16), one per 32-wide K block
    short8 bw[4];
    #pragma unroll
    for (int m = 0; m < 4; ++m) {
        const float* wp = W + (size_t)(w * 16 + col) * IN_F + m * 32 + kg * 8;
        float4 f0 = *(const float4*)wp;
        float4 f1 = *(const float4*)(wp + 4);
        bw[m] = pack_bf16x8(f0, f1);
    }
    float atv_i = att_i[w * OUT_F + col];
    float atv_j = att_j[w * OUT_F + col];

    for (int t = bproj; t < NTILES; t += nproj) {
        int nodeBase = t * 16;
        const float* xp = x + (size_t)(nodeBase + col) * IN_F + kg * 8;
        short8 a[4];
        #pragma unroll
        for (int m = 0; m < 4; ++m) {
            float4 f0 = *(const float4*)(xp + m * 32);
            float4 f1 = *(const float4*)(xp + m * 32 + 4);
            a[m] = pack_bf16x8(f0, f1);
        }
        f32x4 acc = {0.f, 0.f, 0.f, 0.f};
        #pragma unroll
        for (int m = 0; m < 4; ++m)
            acc = __builtin_amdgcn_mfma_f32_16x16x32_bf16(a[m], bw[m], acc, 0, 0, 0);

        // h (bf16) store: lane covers col, rows kg*4+r
        #pragma unroll
        for (int r = 0; r < 4; ++r)
            hb[(size_t)(nodeBase + kg * 4 + r) * OUT_ALL + w * 16 + col] = f2bf(acc[r]);

        // attention dots: reduce acc*att over the 16 cols (lanes of a 16-group)
        float pi0 = acc[0] * atv_i, pi1 = acc[1] * atv_i,
              pi2 = acc[2] * atv_i, pi3 = acc[3] * atv_i;
        float pj0 = acc[0] * atv_j, pj1 = acc[1] * atv_j,
              pj2 = acc[2] * atv_j, pj3 = acc[3] * atv_j;
        #pragma unroll
        for (int d = 1; d < 16; d <<= 1) {
            pi0 += __shfl_xor(pi0, d, 64); pi1 += __shfl_xor(pi1, d, 64);
            pi2 += __shfl_xor(pi2, d, 64); pi3 += __shfl_xor(pi3, d, 64);
            pj0 += __shfl_xor(pj0, d, 64); pj1 += __shfl_xor(pj1, d, 64);
            pj2 += __shfl_xor(pj2, d, 64); pj3 += __shfl_xor(pj3, d, 64);
        }
        if (col == 0) {
            int nb = nodeBase + kg * 4;
            ai[(nb + 0) * HEADS + w] = pi0; aj[(nb + 0) * HEADS + w] = pj0;
            ai[(nb + 1) * HEADS + w] = pi1; aj[(nb + 1) * HEADS + w] = pj1;
            ai[(nb + 2) * HEADS + w] = pi2; aj[(nb + 2) * HEADS + w] = pj2;
            ai[(nb + 3) * HEADS + w] = pi3; aj[(nb + 3) * HEADS + w] = pj3;
        }
    }
}

// ---- Kernel 2: per-node gather + softmax (chain walk, bf16 h) ------------
__global__ __launch_bounds__(256) void gather_kernel(
    const int* __restrict__ head, const u64* __restrict__ link,
    const ushort* __restrict__ hb, const float* __restrict__ ai,
    const float* __restrict__ aj, float* __restrict__ out)
{
    int node = blockIdx.x * 16 + (threadIdx.x >> 4);
    if (node >= N_NODES) return;
    int sub  = threadIdx.x & 15;
    int headq = sub >> 2;
    float aiv = ai[node * HEADS + headq];
    float4 acc = {0.f, 0.f, 0.f, 0.f};
    float  den = 0.f;
    int cur = head[node];
    for (int it = 0; it < 128 && cur >= 0; ++it) {
        u64 v = link[cur];                       // broadcast across 16 lanes
        int src = (int)(unsigned)(v & 0xffffffffu);
        cur = (int)(unsigned)(v >> 32);
        float av = aiv + aj[src * HEADS + headq];
        av = av > 0.f ? av : 0.01f * av;
        float ex = __expf(av);
        den += ex;
        ushort4 hv = *(const ushort4*)(hb + (size_t)src * OUT_ALL + sub * 4);
        acc.x += ex * bf2f(hv.x); acc.y += ex * bf2f(hv.y);
        acc.z += ex * bf2f(hv.z); acc.w += ex * bf2f(hv.w);
    }
    float inv = 1.0f / (den + 1e-16f);
    acc.x *= inv; acc.y *= inv; acc.z *= inv; acc.w *= inv;
    *(float4*)(out + (size_t)node * OUT_ALL + sub * 4) = acc;
}

extern "C" void kernel_launch(void* const* d_in, const int* in_sizes, int n_in,
                              void* d_out, int out_size, void* d_ws, size_t ws_size,
                              hipStream_t stream) {
    const float* x     = (const float*)d_in[0];
    const int*   ei    = (const int*)d_in[1];
    const float* W     = (const float*)d_in[2];
    const float* att_i = (const float*)d_in[3];
    const float* att_j = (const float*)d_in[4];
    float* out = (float*)d_out;

    char* ws = (char*)d_ws;
    size_t off = 0;
    auto alloc = [&](size_t bytes) {
        void* p = ws + off;
        off += (bytes + 255) & ~(size_t)255;
        return p;
    };
    ushort* hb   = (ushort*)alloc((size_t)N_NODES * OUT_ALL * 2);  // 12.8 MB
    float*  ai   = (float*)alloc((size_t)N_NODES * HEADS * 4);     // 1.6 MB
    float*  aj   = (float*)alloc((size_t)N_NODES * HEADS * 4);     // 1.6 MB
    int*    head = (int*)alloc((size_t)N_NODES * 4);               // 0.4 MB
    u64*    link = (u64*)alloc((size_t)N_EDGES * 8);               // 12.8 MB

    hipMemsetAsync(head, 0xFF, (size_t)N_NODES * 4, stream);   // head = -1
    proj_scatter_kernel<<<TOTAL_BLOCKS, 256, 0, stream>>>(
        x, W, att_i, att_j, ei, hb, ai, aj, head, link);
    gather_kernel<<<(N_NODES + 15) / 16, 256, 0, stream>>>(
        head, link, hb, ai, aj, out);
}